// Round 6
// baseline (688.518 us; speedup 1.0000x reference)
//
#include <hip/hip_runtime.h>
#include <hip/hip_bf16.h>
#include <math.h>

#define NB 4
#define NC 16
#define NN 8192
#define NK 9
#define LIST 12   /* approx top-K kept per slice (9 + 3 margin) */
#define CHUNK 8   /* candidates per flush chunk; CAP == CHUNK is worst-case exact */

// ---------------------------------------------------------------------------
// Kernel 0: transpose x[b][c][n] -> xt[b][n][c] (64B rows, s_load-friendly);
// numpy-replica f32 norm ns32 (squares rounded, sequential adds, no FMA);
// nsk = 128 + 0.5*ns (always-positive surrogate-key offset).
// ---------------------------------------------------------------------------
__global__ void prep_kernel(const float* __restrict__ x,
                            float* __restrict__ xt,
                            float* __restrict__ ns32,
                            float* __restrict__ nsk) {
    int t = blockIdx.x * blockDim.x + threadIdx.x; // 0..32767
    int b = t >> 13;
    int m = t & (NN - 1);
    const float* xb = x + (size_t)b * NC * NN;
    float v[NC];
#pragma unroll
    for (int c = 0; c < NC; ++c) v[c] = xb[(size_t)c * NN + m]; // coalesced
    float s = __fmul_rn(v[0], v[0]);
#pragma unroll
    for (int c = 1; c < NC; ++c) s = __fadd_rn(s, __fmul_rn(v[c], v[c]));
    float* o = xt + (size_t)t * NC;
#pragma unroll
    for (int c = 0; c < NC; ++c) o[c] = v[c];
    ns32[t] = s;
    nsk[t] = 128.0f + 0.5f * s;
}

// Sorted (ascending) 12-slot u64 bubble insert; key = (k32<<32)|index.
// Inserting ~0ULL is a no-op (used to predicate without branching).
__device__ __forceinline__ void insert12(unsigned long long* lst,
                                         unsigned long long key) {
#pragma unroll
    for (int i = 0; i < LIST; ++i) {
        unsigned long long a = lst[i];
        bool sm = key < a;
        unsigned long long lo = sm ? key : a;
        key = sm ? a : key;
        lst[i] = lo;
    }
}

// ---------------------------------------------------------------------------
// Kernel 1: approximate top-12 per (row, m-slice) by the surrogate key
// 128 + 0.5*ns_m - dot(x_n, x_m)  (monotone in dist within a row; diag is
// provably the slice minimum; all keys positive so f32-bit order = value
// order). Candidate data (xt row + nsk) is loaded at wave-uniform addresses
// derived purely from block-uniform induction -> scalar-pipe loads.
// Selection is BRANCHLESS: every key is ds_written to slot cnt of a per-lane
// LDS stack; cnt advances only on hit (k32 < thr). Flush per 8-cand chunk
// (CAP=8 => lossless by construction), threshold refreshed per chunk.
// ---------------------------------------------------------------------------
template <int QSPLIT>
__global__ __launch_bounds__(256) void topk_kernel(
        const float* __restrict__ xt, const float* __restrict__ nsk,
        unsigned short* __restrict__ cand) {
    constexpr int QLEN = NN / QSPLIT;
    __shared__ unsigned long long stk[CHUNK * 256];
    const int tid = threadIdx.x;
    const int lane = tid & 63;
    const int wid = blockIdx.x * 4 + (tid >> 6);   // global wave id
    const int q = wid & (QSPLIT - 1);
    const int rg = wid / QSPLIT;                   // 0..511, uniform
    const int b = rg >> 7;                         // uniform
    const int n = (rg * 64 + lane) & (NN - 1);
    const float* xb = xt + (size_t)b * NN * NC;    // uniform base
    const float* nk = nsk + b * NN;                // uniform base
    const float* xrow = xb + (size_t)n * NC;
    float xr[NC];
#pragma unroll
    for (int c = 0; c < NC; ++c) xr[c] = -xrow[c];

    unsigned long long lst[LIST];
#pragma unroll
    for (int i = 0; i < LIST; ++i) lst[i] = ~0ULL;
    unsigned long long* stkrow = stk + tid;        // lane-contiguous rows
    const int m0 = q * QLEN;

    // Prologue: first 16 candidates unconditionally (builds a real threshold).
#pragma unroll 4
    for (int t = 0; t < 16; ++t) {
        const int m = m0 + t;                      // uniform
        const float* col = xb + (size_t)m * NC;    // uniform -> scalar loads
        float a0 = nk[m];
        float a1 = xr[1] * col[1];
        a0 = fmaf(xr[0], col[0], a0);
#pragma unroll
        for (int c = 2; c < NC; c += 2) {
            a0 = fmaf(xr[c], col[c], a0);
            a1 = fmaf(xr[c + 1], col[c + 1], a1);
        }
        const unsigned k32 = __float_as_uint(a0 + a1);
        insert12(lst, ((unsigned long long)k32 << 32) | (unsigned)m);
    }

    // Main loop: chunks of 8, branchless push, per-chunk flush + thr refresh.
    for (int mw = m0 + 16; mw < m0 + QLEN; mw += CHUNK) {
        const unsigned thr = (unsigned)(lst[LIST - 1] >> 32);
        int cnt = 0;
#pragma unroll
        for (int j = 0; j < CHUNK; ++j) {
            const int m = mw + j;                  // uniform
            const float* col = xb + (size_t)m * NC;
            float a0 = nk[m];
            float a1 = xr[1] * col[1];
            a0 = fmaf(xr[0], col[0], a0);
#pragma unroll
            for (int c = 2; c < NC; c += 2) {
                a0 = fmaf(xr[c], col[c], a0);
                a1 = fmaf(xr[c + 1], col[c + 1], a1);
            }
            const unsigned k32 = __float_as_uint(a0 + a1);
            stkrow[cnt * 256] = ((unsigned long long)k32 << 32) | (unsigned)m;
            cnt += (k32 < thr) ? 1 : 0;            // hit locks its slot
        }
        if (__any(cnt != 0)) {                     // flush (usually short)
            for (int jj = 0; jj < CHUNK; ++jj) {
                if (!__any(cnt > jj)) break;
                const unsigned long long k = stkrow[jj * 256];
                const bool valid = (jj < cnt) &&
                    ((unsigned)(k >> 32) < (unsigned)(lst[LIST - 1] >> 32));
                insert12(lst, valid ? k : ~0ULL);  // ~0 insert = no-op
            }
        }
    }

    unsigned short* o =
        cand + (size_t)(rg * 64 + lane) * (QSPLIT * LIST) + q * LIST;
#pragma unroll
    for (int i = 0; i < LIST; ++i) o[i] = (unsigned short)(lst[i] & 0xFFFFu);
}

// ---------------------------------------------------------------------------
// Kernel 2: exact re-rank of the CANDN union candidates with the BIT-EXACT
// numpy-f32 replica distance (verified R3):
//   dot  = sequential fmaf chain c=0..15 (npyv_muladd)
//   dist = fl( fl(ns_n + ns_m) - fl(2*dot) ), max(dist,0), diag k32=0.
// Packed u64 keys (monotone for dist>=0), skip-guarded 9-slot insert, then
// the 16x(16x9) conv contraction + bias.
// ---------------------------------------------------------------------------
template <int CANDN>
__global__ __launch_bounds__(256) void finish_kernel(
        const float* __restrict__ xt, const float* __restrict__ ns32,
        const unsigned short* __restrict__ cand,
        const float* __restrict__ W, const float* __restrict__ bias,
        float* __restrict__ out) {
    const int row = blockIdx.x * 256 + threadIdx.x; // 0..32767
    const int b = row >> 13;                        // uniform (256 | 8192)
    const int n = row & (NN - 1);
    const float* xb = xt + (size_t)b * NN * NC;
    const float* xrow = xb + (size_t)n * NC;
    float xv[NC];
#pragma unroll
    for (int c = 0; c < NC; ++c) xv[c] = xrow[c];
    const float nsn = ns32[row];
    const float* nsb = ns32 + b * NN;

    unsigned long long lst[NK];
#pragma unroll
    for (int i = 0; i < NK; ++i) lst[i] = ~0ULL;

    const unsigned short* cl = cand + (size_t)row * CANDN;
    for (int j = 0; j < CANDN; ++j) {
        const int m = cl[j];
        const float* col = xb + (size_t)m * NC;
        float dot = 0.0f;
#pragma unroll
        for (int c = 0; c < NC; ++c)
            dot = fmaf(xv[c], col[c], dot);   // npyv_muladd replica (FMA)
        float dist = __fsub_rn(__fadd_rn(nsn, nsb[m]), __fmul_rn(2.0f, dot));
        dist = fmaxf(dist, 0.0f);
        const unsigned k32 = (m == n) ? 0u
                                      : (__float_as_uint(dist) | 0x80000000u);
        unsigned long long key =
            ((unsigned long long)k32 << 32) | (unsigned)m;
        if (key < lst[NK - 1]) {
#pragma unroll
            for (int i = 0; i < NK; ++i) {
                unsigned long long a = lst[i];
                bool sm = key < a;
                unsigned long long lo = sm ? key : a;
                unsigned long long hi = sm ? a : key;
                lst[i] = lo;
                key = hi;
            }
        }
    }

    float acc[NC];
#pragma unroll
    for (int o = 0; o < NC; ++o) acc[o] = bias[o];
    for (int k = 0; k < NK; ++k) {
        const float* col = xb + (size_t)(lst[k] & 0xFFFFu) * NC;
        float cv[NC];
#pragma unroll
        for (int c = 0; c < NC; ++c) cv[c] = col[c];
#pragma unroll
        for (int o = 0; o < NC; ++o) {
            float a = acc[o];
#pragma unroll
            for (int c = 0; c < NC; ++c)
                a = fmaf(W[o * (NC * NK) + c * NK + k], cv[c], a);
            acc[o] = a;
        }
    }
    float* ob = out + (size_t)b * NC * NN + n;
#pragma unroll
    for (int o = 0; o < NC; ++o) ob[(size_t)o * NN] = acc[o];
}

extern "C" void kernel_launch(void* const* d_in, const int* in_sizes, int n_in,
                              void* d_out, int out_size, void* d_ws, size_t ws_size,
                              hipStream_t stream) {
    const float* x = (const float*)d_in[0];     // [4][16][8192]
    const float* W = (const float*)d_in[1];     // [16][16][9]
    const float* bias = (const float*)d_in[2];  // [16]
    float* out = (float*)d_out;                 // [4][16][8192]

    char* ws = (char*)d_ws;
    float* xt = (float*)ws;                                          // 2 MB
    float* ns32 = (float*)(ws + 2097152);                            // 128 KB
    float* nsk = (float*)(ws + 2097152 + 131072);                    // 128 KB
    unsigned short* cand = (unsigned short*)(ws + 2097152 + 262144);

    const size_t base = 2097152 + 262144;
    auto need = [&](int Q) {
        return base + (size_t)NB * NN * (size_t)(Q * LIST) * 2;
    };

    prep_kernel<<<(NB * NN) / 256, 256, 0, stream>>>(x, xt, ns32, nsk);

    if (ws_size >= need(16)) {          // 8192 waves, 32/CU
        topk_kernel<16><<<128 * 16, 256, 0, stream>>>(xt, nsk, cand);
        finish_kernel<16 * LIST><<<128, 256, 0, stream>>>(xt, ns32, cand, W, bias, out);
    } else if (ws_size >= need(8)) {    // 4096 waves, 16/CU
        topk_kernel<8><<<128 * 8, 256, 0, stream>>>(xt, nsk, cand);
        finish_kernel<8 * LIST><<<128, 256, 0, stream>>>(xt, ns32, cand, W, bias, out);
    } else {                            // 2048 waves, 8/CU
        topk_kernel<4><<<128 * 4, 256, 0, stream>>>(xt, nsk, cand);
        finish_kernel<4 * LIST><<<128, 256, 0, stream>>>(xt, ns32, cand, W, bias, out);
    }
}

// Round 7
// 500.494 us; speedup vs baseline: 1.3757x; 1.3757x over previous
//
#include <hip/hip_runtime.h>
#include <hip/hip_bf16.h>
#include <math.h>

#define NB 4
#define NC 16
#define NN 8192
#define NK 9
#define LIST 12   /* approx top-K kept per slice (9 + 3 margin) */
#define CHUNK 8   /* candidates per flush chunk; CAP == CHUNK is worst-case exact */

// ---------------------------------------------------------------------------
// Kernel 0: transpose x[b][c][n] -> xt[b][n][c] (64B rows, s_load-friendly);
// numpy-replica f32 norm ns32 (squares rounded, sequential adds, no FMA);
// nsk = 128 + 0.5*ns (always-positive surrogate-key offset).
// ---------------------------------------------------------------------------
__global__ void prep_kernel(const float* __restrict__ x,
                            float* __restrict__ xt,
                            float* __restrict__ ns32,
                            float* __restrict__ nsk) {
    int t = blockIdx.x * blockDim.x + threadIdx.x; // 0..32767
    int b = t >> 13;
    int m = t & (NN - 1);
    const float* xb = x + (size_t)b * NC * NN;
    float v[NC];
#pragma unroll
    for (int c = 0; c < NC; ++c) v[c] = xb[(size_t)c * NN + m]; // coalesced
    float s = __fmul_rn(v[0], v[0]);
#pragma unroll
    for (int c = 1; c < NC; ++c) s = __fadd_rn(s, __fmul_rn(v[c], v[c]));
    float* o = xt + (size_t)t * NC;
#pragma unroll
    for (int c = 0; c < NC; ++c) o[c] = v[c];
    ns32[t] = s;
    nsk[t] = 128.0f + 0.5f * s;
}

// Sorted (ascending) 12-slot u64 bubble insert; key = (k32<<32)|index.
// Inserting ~0ULL is a no-op (used to predicate without branching).
__device__ __forceinline__ void insert12(unsigned long long* lst,
                                         unsigned long long key) {
#pragma unroll
    for (int i = 0; i < LIST; ++i) {
        unsigned long long a = lst[i];
        bool sm = key < a;
        unsigned long long lo = sm ? key : a;
        key = sm ? a : key;
        lst[i] = lo;
    }
}

// ---------------------------------------------------------------------------
// Kernel 1: approximate top-12 per (row, m-slice) by the surrogate key
// 128 + 0.5*ns_m - dot(x_n, x_m). BLOCK-UNIFORM candidate walk: q and the
// row-group are derived from blockIdx ONLY (all 4 waves share one m-slice,
// each thread owns one of the block's 256 rows), so divergence analysis
// proves col/nsk addresses uniform -> scalar-pipe s_load, and the FMA chain
// consumes SGPR operands. Selection is branchless: every key is ds_written
// to slot cnt of a per-lane LDS stack; cnt advances only on hit (k32 < thr).
// Flush per 8-cand chunk (CAP=8 => lossless), threshold refreshed per chunk.
// ---------------------------------------------------------------------------
template <int QSPLIT>
__global__ __launch_bounds__(256) void topk_kernel(
        const float* __restrict__ xt, const float* __restrict__ nsk,
        unsigned short* __restrict__ cand) {
    constexpr int QLEN = NN / QSPLIT;
    __shared__ unsigned long long stk[CHUNK * 256];
    const int tid = threadIdx.x;
    const int rg = blockIdx.x / QSPLIT;   // 0..127, uniform 256-row group
    const int q = blockIdx.x % QSPLIT;    // uniform m-slice
    const int row = rg * 256 + tid;       // 0..32767
    const int b = rg >> 5;                // uniform (32 groups per batch)
    const int n = row & (NN - 1);
    const float* xb = xt + (size_t)b * NN * NC;    // uniform base
    const float* nk = nsk + b * NN;                // uniform base
    const float* xrow = xb + (size_t)n * NC;
    float xr[NC];
#pragma unroll
    for (int c = 0; c < NC; ++c) xr[c] = -xrow[c];

    unsigned long long lst[LIST];
#pragma unroll
    for (int i = 0; i < LIST; ++i) lst[i] = ~0ULL;
    unsigned long long* stkrow = stk + tid;        // lane-contiguous rows
    const int m0 = q * QLEN;

    // Prologue: first 16 candidates unconditionally (builds a real threshold).
#pragma unroll 4
    for (int t = 0; t < 16; ++t) {
        const int m = m0 + t;                      // uniform
        const float* col = xb + (size_t)m * NC;    // uniform -> scalar loads
        float a0 = nk[m];
        float a1 = xr[1] * col[1];
        a0 = fmaf(xr[0], col[0], a0);
#pragma unroll
        for (int c = 2; c < NC; c += 2) {
            a0 = fmaf(xr[c], col[c], a0);
            a1 = fmaf(xr[c + 1], col[c + 1], a1);
        }
        const unsigned k32 = __float_as_uint(a0 + a1);
        insert12(lst, ((unsigned long long)k32 << 32) | (unsigned)m);
    }

    // Main loop: chunks of 8, branchless push, per-chunk flush + thr refresh.
    for (int mw = m0 + 16; mw < m0 + QLEN; mw += CHUNK) {
        const unsigned thr = (unsigned)(lst[LIST - 1] >> 32);
        int cnt = 0;
#pragma unroll
        for (int j = 0; j < CHUNK; ++j) {
            const int m = mw + j;                  // uniform
            const float* col = xb + (size_t)m * NC;
            float a0 = nk[m];
            float a1 = xr[1] * col[1];
            a0 = fmaf(xr[0], col[0], a0);
#pragma unroll
            for (int c = 2; c < NC; c += 2) {
                a0 = fmaf(xr[c], col[c], a0);
                a1 = fmaf(xr[c + 1], col[c + 1], a1);
            }
            const unsigned k32 = __float_as_uint(a0 + a1);
            stkrow[cnt * 256] = ((unsigned long long)k32 << 32) | (unsigned)m;
            cnt += (k32 < thr) ? 1 : 0;            // hit locks its slot
        }
        if (__any(cnt != 0)) {                     // flush (usually short)
            for (int jj = 0; jj < CHUNK; ++jj) {
                if (!__any(cnt > jj)) break;
                const unsigned long long k = stkrow[jj * 256];
                const bool valid = (jj < cnt) &&
                    ((unsigned)(k >> 32) < (unsigned)(lst[LIST - 1] >> 32));
                insert12(lst, valid ? k : ~0ULL);  // ~0 insert = no-op
            }
        }
    }

    unsigned short* o = cand + (size_t)row * (QSPLIT * LIST) + q * LIST;
#pragma unroll
    for (int i = 0; i < LIST; ++i) o[i] = (unsigned short)(lst[i] & 0xFFFFu);
}

// ---------------------------------------------------------------------------
// Kernel 2: exact re-rank of the CANDN union candidates with the BIT-EXACT
// numpy-f32 replica distance (verified R3):
//   dot  = sequential fmaf chain c=0..15 (npyv_muladd)
//   dist = fl( fl(ns_n + ns_m) - fl(2*dot) ), max(dist,0), diag k32=0.
// Packed u64 keys (monotone for dist>=0), skip-guarded 9-slot insert, then
// the 16x(16x9) conv contraction + bias.
// ---------------------------------------------------------------------------
template <int CANDN>
__global__ __launch_bounds__(256) void finish_kernel(
        const float* __restrict__ xt, const float* __restrict__ ns32,
        const unsigned short* __restrict__ cand,
        const float* __restrict__ W, const float* __restrict__ bias,
        float* __restrict__ out) {
    const int row = blockIdx.x * 256 + threadIdx.x; // 0..32767
    const int b = row >> 13;                        // uniform (256 | 8192)
    const int n = row & (NN - 1);
    const float* xb = xt + (size_t)b * NN * NC;
    const float* xrow = xb + (size_t)n * NC;
    float xv[NC];
#pragma unroll
    for (int c = 0; c < NC; ++c) xv[c] = xrow[c];
    const float nsn = ns32[row];
    const float* nsb = ns32 + b * NN;

    unsigned long long lst[NK];
#pragma unroll
    for (int i = 0; i < NK; ++i) lst[i] = ~0ULL;

    const unsigned short* cl = cand + (size_t)row * CANDN;
    for (int j = 0; j < CANDN; ++j) {
        const int m = cl[j];
        const float* col = xb + (size_t)m * NC;
        float dot = 0.0f;
#pragma unroll
        for (int c = 0; c < NC; ++c)
            dot = fmaf(xv[c], col[c], dot);   // npyv_muladd replica (FMA)
        float dist = __fsub_rn(__fadd_rn(nsn, nsb[m]), __fmul_rn(2.0f, dot));
        dist = fmaxf(dist, 0.0f);
        const unsigned k32 = (m == n) ? 0u
                                      : (__float_as_uint(dist) | 0x80000000u);
        unsigned long long key =
            ((unsigned long long)k32 << 32) | (unsigned)m;
        if (key < lst[NK - 1]) {
#pragma unroll
            for (int i = 0; i < NK; ++i) {
                unsigned long long a = lst[i];
                bool sm = key < a;
                unsigned long long lo = sm ? key : a;
                unsigned long long hi = sm ? a : key;
                lst[i] = lo;
                key = hi;
            }
        }
    }

    float acc[NC];
#pragma unroll
    for (int o = 0; o < NC; ++o) acc[o] = bias[o];
    for (int k = 0; k < NK; ++k) {
        const float* col = xb + (size_t)(lst[k] & 0xFFFFu) * NC;
        float cv[NC];
#pragma unroll
        for (int c = 0; c < NC; ++c) cv[c] = col[c];
#pragma unroll
        for (int o = 0; o < NC; ++o) {
            float a = acc[o];
#pragma unroll
            for (int c = 0; c < NC; ++c)
                a = fmaf(W[o * (NC * NK) + c * NK + k], cv[c], a);
            acc[o] = a;
        }
    }
    float* ob = out + (size_t)b * NC * NN + n;
#pragma unroll
    for (int o = 0; o < NC; ++o) ob[(size_t)o * NN] = acc[o];
}

extern "C" void kernel_launch(void* const* d_in, const int* in_sizes, int n_in,
                              void* d_out, int out_size, void* d_ws, size_t ws_size,
                              hipStream_t stream) {
    const float* x = (const float*)d_in[0];     // [4][16][8192]
    const float* W = (const float*)d_in[1];     // [16][16][9]
    const float* bias = (const float*)d_in[2];  // [16]
    float* out = (float*)d_out;                 // [4][16][8192]

    char* ws = (char*)d_ws;
    float* xt = (float*)ws;                                          // 2 MB
    float* ns32 = (float*)(ws + 2097152);                            // 128 KB
    float* nsk = (float*)(ws + 2097152 + 131072);                    // 128 KB
    unsigned short* cand = (unsigned short*)(ws + 2097152 + 262144);

    const size_t base = 2097152 + 262144;
    auto need = [&](int Q) {
        return base + (size_t)NB * NN * (size_t)(Q * LIST) * 2;
    };

    prep_kernel<<<(NB * NN) / 256, 256, 0, stream>>>(x, xt, ns32, nsk);

    if (ws_size >= need(16)) {          // 2048 blocks, 8/CU, 32 waves/CU
        topk_kernel<16><<<128 * 16, 256, 0, stream>>>(xt, nsk, cand);
        finish_kernel<16 * LIST><<<128, 256, 0, stream>>>(xt, ns32, cand, W, bias, out);
    } else if (ws_size >= need(8)) {    // 1024 blocks, 4/CU, 16 waves/CU
        topk_kernel<8><<<128 * 8, 256, 0, stream>>>(xt, nsk, cand);
        finish_kernel<8 * LIST><<<128, 256, 0, stream>>>(xt, ns32, cand, W, bias, out);
    } else {                            // 512 blocks, 2/CU, 8 waves/CU
        topk_kernel<4><<<128 * 4, 256, 0, stream>>>(xt, nsk, cand);
        finish_kernel<4 * LIST><<<128, 256, 0, stream>>>(xt, ns32, cand, W, bias, out);
    }
}

// Round 8
// 454.758 us; speedup vs baseline: 1.5140x; 1.1006x over previous
//
#include <hip/hip_runtime.h>
#include <hip/hip_bf16.h>
#include <math.h>

#define NB 4
#define NC 16
#define NN 8192
#define NK 9
#define LIST 12   /* approx top-K kept per slice (9 + 3 margin) */

typedef float v2f __attribute__((ext_vector_type(2)));

// ws layout (bytes)
#define OFF_NS   2097152
#define OFF_NSK  2228224
#define OFF_THR  2359296
#define OFF_NBR  2490368
#define OFF_CAND 3145728

// ---------------------------------------------------------------------------
// Kernel 0: transpose x[b][c][n] -> xt[b][n][c] (64B rows, s_load-friendly);
// numpy-replica f32 norm ns32 (squares rounded, sequential adds, no FMA);
// nsk = 128 + 0.5*ns (always-positive surrogate-key offset); init the
// per-row shared-threshold cells to +inf (re-done every launch).
// ---------------------------------------------------------------------------
__global__ void prep_kernel(const float* __restrict__ x,
                            float* __restrict__ xt,
                            float* __restrict__ ns32,
                            float* __restrict__ nsk,
                            unsigned* __restrict__ thrsh) {
    int t = blockIdx.x * blockDim.x + threadIdx.x; // 0..32767
    int b = t >> 13;
    int m = t & (NN - 1);
    const float* xb = x + (size_t)b * NC * NN;
    float v[NC];
#pragma unroll
    for (int c = 0; c < NC; ++c) v[c] = xb[(size_t)c * NN + m]; // coalesced
    float s = __fmul_rn(v[0], v[0]);
#pragma unroll
    for (int c = 1; c < NC; ++c) s = __fadd_rn(s, __fmul_rn(v[c], v[c]));
    float* o = xt + (size_t)t * NC;
#pragma unroll
    for (int c = 0; c < NC; ++c) o[c] = v[c];
    ns32[t] = s;
    nsk[t] = 128.0f + 0.5f * s;
    thrsh[t] = 0xFFFFFFFFu;
}

// Sorted (ascending) 12-slot u64 bubble insert; key = (k32<<32)|index.
// Inserting ~0ULL is a no-op (used to predicate without branching).
__device__ __forceinline__ void insert12(unsigned long long* lst,
                                         unsigned long long key) {
#pragma unroll
    for (int i = 0; i < LIST; ++i) {
        unsigned long long a = lst[i];
        bool sm = key < a;
        unsigned long long lo = sm ? key : a;
        key = sm ? a : key;
        lst[i] = lo;
    }
}

// Surrogate key: 128 + 0.5*ns_m - dot(x_n, x_m), 4-way split accumulation,
// packed-f32 FMA (v_pk_fma_f32). Positive by construction -> f32-bit order.
__device__ __forceinline__ unsigned surr_key(const float* __restrict__ xb,
                                             const float* __restrict__ nk,
                                             int m, const v2f* xr2) {
    const v2f* c2 = (const v2f*)(xb + (size_t)m * NC);  // uniform -> s_load
    v2f a0, a1;
    a0.x = nk[m]; a0.y = 0.f;
    a1.x = 0.f;   a1.y = 0.f;
#if __has_builtin(__builtin_elementwise_fma)
#pragma unroll
    for (int i = 0; i < 8; i += 2) {
        a0 = __builtin_elementwise_fma(xr2[i], c2[i], a0);
        a1 = __builtin_elementwise_fma(xr2[i + 1], c2[i + 1], a1);
    }
#else
#pragma unroll
    for (int i = 0; i < 8; i += 2) {
        a0.x = fmaf(xr2[i].x, c2[i].x, a0.x);
        a0.y = fmaf(xr2[i].y, c2[i].y, a0.y);
        a1.x = fmaf(xr2[i + 1].x, c2[i + 1].x, a1.x);
        a1.y = fmaf(xr2[i + 1].y, c2[i + 1].y, a1.y);
    }
#endif
    v2f s = a0 + a1;
    return __float_as_uint(s.x + s.y);
}

// ---------------------------------------------------------------------------
// Kernel 1: approximate top-12 per (row, m-slice). Block-uniform candidate
// walk (proved R7: scalar-pipe col/nsk loads). NEW: (a) per-candidate k32 is
// written to its OWN fixed LDS slot (imm offset) + hit recorded in a bitmask;
// flush walks set bits and rebuilds m from the slot index -> no per-cand addr
// math, capacity-exact. (b) cross-slice shared threshold per row via
// atomicMin: thr = min(local12th-1, shared); k32 <= thr. Shared cell only
// decreases and is always >= global 12th-smallest (order stats over subsets
// dominate), stale cross-XCD reads are larger = safe, so the union of slice
// lists still contains the global approx top-12 -> output deterministic.
// ---------------------------------------------------------------------------
template <int QSPLIT>
__global__ __launch_bounds__(256) void topk_kernel(
        const float* __restrict__ xt, const float* __restrict__ nsk,
        unsigned* thrsh, unsigned short* __restrict__ cand) {
    constexpr int QLEN = NN / QSPLIT;
    constexpr int CHUNK = 16;
    __shared__ unsigned stk[CHUNK * 256];
    const int tid = threadIdx.x;
    const int rg = blockIdx.x / QSPLIT;   // uniform 256-row group
    const int q = blockIdx.x % QSPLIT;    // uniform m-slice
    const int row = rg * 256 + tid;       // 0..32767
    const int b = rg >> 5;                // uniform
    const int n = row & (NN - 1);
    const float* xb = xt + (size_t)b * NN * NC;    // uniform base
    const float* nk = nsk + b * NN;                // uniform base
    v2f xr2[8];
    {
        const float* xrow = xb + (size_t)n * NC;
#pragma unroll
        for (int i = 0; i < 8; ++i) {
            xr2[i].x = -xrow[2 * i];
            xr2[i].y = -xrow[2 * i + 1];
        }
    }

    unsigned long long lst[LIST];
#pragma unroll
    for (int i = 0; i < LIST; ++i) lst[i] = ~0ULL;
    const int m0 = q * QLEN;

    // Prologue: first 16 candidates unconditionally (real threshold).
#pragma unroll 4
    for (int t = 0; t < 16; ++t) {
        const unsigned k32 = surr_key(xb, nk, m0 + t, xr2);
        insert12(lst, ((unsigned long long)k32 << 32) | (unsigned)(m0 + t));
    }
    unsigned* mythr = thrsh + row;
    atomicMin(mythr, (unsigned)(lst[LIST - 1] >> 32));
    bool changed = false;

    for (int mw = m0 + 16; mw < m0 + QLEN; mw += CHUNK) {
        const unsigned thr_loc = (unsigned)(lst[LIST - 1] >> 32);
        const unsigned thr_sh = *(volatile const unsigned*)mythr;
        const unsigned tl1 = thr_loc - 1u;
        const unsigned thr = tl1 < thr_sh ? tl1 : thr_sh; // hit iff k32 <= thr
        unsigned mask = 0u;
#pragma unroll
        for (int j = 0; j < CHUNK; ++j) {
            const unsigned k32 = surr_key(xb, nk, mw + j, xr2);
            stk[j * 256 + tid] = k32;                  // fixed imm-offset slot
            mask |= (k32 <= thr) ? (1u << j) : 0u;
        }
        while (__any(mask != 0u)) {
            const int j = __ffs(mask) - 1;             // -1 when mask==0
            const int j0 = j < 0 ? 0 : j;
            const unsigned k32 = stk[j0 * 256 + tid];
            const bool valid = (mask != 0u) &&
                (k32 < (unsigned)(lst[LIST - 1] >> 32));
            const unsigned long long key =
                ((unsigned long long)k32 << 32) | (unsigned)(mw + j0);
            insert12(lst, valid ? key : ~0ULL);        // ~0 insert = no-op
            changed |= valid;
            mask &= mask - 1u;
        }
        if (((mw >> 4) & 1) && __any(changed)) {       // publish every 2 chunks
            if (changed) atomicMin(mythr, (unsigned)(lst[LIST - 1] >> 32));
            changed = false;
        }
    }

    unsigned short* o = cand + (size_t)row * (QSPLIT * LIST) + q * LIST;
#pragma unroll
    for (int i = 0; i < LIST; ++i) o[i] = (unsigned short)(lst[i] & 0xFFFFu);
}

// ---------------------------------------------------------------------------
// Kernel 2: exact re-rank of the CANDN union candidates with the BIT-EXACT
// numpy-f32 replica distance (verified R3):
//   dot  = sequential fmaf chain c=0..15 (npyv_muladd)
//   dist = fl( fl(ns_n + ns_m) - fl(2*dot) ), max(dist,0), diag k32=0.
// Writes the 9 selected neighbor indices per row (sorted by (dist, idx)).
// ---------------------------------------------------------------------------
template <int CANDN>
__global__ __launch_bounds__(256) void rerank_kernel(
        const float* __restrict__ xt, const float* __restrict__ ns32,
        const unsigned short* __restrict__ cand,
        unsigned short* __restrict__ nbr) {
    const int row = blockIdx.x * 256 + threadIdx.x; // 0..32767
    const int b = row >> 13;                        // uniform
    const int n = row & (NN - 1);
    const float* xb = xt + (size_t)b * NN * NC;
    const float* xrow = xb + (size_t)n * NC;
    float xv[NC];
#pragma unroll
    for (int c = 0; c < NC; ++c) xv[c] = xrow[c];
    const float nsn = ns32[row];
    const float* nsb = ns32 + b * NN;

    unsigned long long lst[NK];
#pragma unroll
    for (int i = 0; i < NK; ++i) lst[i] = ~0ULL;

    const unsigned short* cl = cand + (size_t)row * CANDN;
    for (int j = 0; j < CANDN; ++j) {
        const int m = cl[j];
        const float* col = xb + (size_t)m * NC;
        float dot = 0.0f;
#pragma unroll
        for (int c = 0; c < NC; ++c)
            dot = fmaf(xv[c], col[c], dot);   // npyv_muladd replica (FMA)
        float dist = __fsub_rn(__fadd_rn(nsn, nsb[m]), __fmul_rn(2.0f, dot));
        dist = fmaxf(dist, 0.0f);
        const unsigned k32 = (m == n) ? 0u
                                      : (__float_as_uint(dist) | 0x80000000u);
        unsigned long long key =
            ((unsigned long long)k32 << 32) | (unsigned)m;
        if (key < lst[NK - 1]) {
#pragma unroll
            for (int i = 0; i < NK; ++i) {
                unsigned long long a = lst[i];
                bool sm = key < a;
                unsigned long long lo = sm ? key : a;
                unsigned long long hi = sm ? a : key;
                lst[i] = lo;
                key = hi;
            }
        }
    }

    unsigned short* o = nbr + (size_t)row * NK;
#pragma unroll
    for (int k = 0; k < NK; ++k) o[k] = (unsigned short)(lst[k] & 0xFFFFu);
}

// ---------------------------------------------------------------------------
// Kernel 3: conv epilogue. Block-uniform output channel ob -> the W slice
// and bias are scalar-pipe loads; each thread gathers its row's 9 neighbor
// columns (vector dwordx4 loads) and does 144 FMAs. k-major/c-minor
// accumulation order (same as R7; output tolerance is fp-noise level).
// ---------------------------------------------------------------------------
__global__ __launch_bounds__(256) void conv_kernel(
        const float* __restrict__ xt, const unsigned short* __restrict__ nbr,
        const float* __restrict__ W, const float* __restrict__ bias,
        float* __restrict__ out) {
    const int tid = threadIdx.x;
    const int ob = blockIdx.x >> 7;       // 0..15, uniform
    const int rb = blockIdx.x & 127;      // row block
    const int row = rb * 256 + tid;       // 0..32767
    const int b = rb >> 5;                // uniform
    const int n = row & (NN - 1);
    const float* xb = xt + (size_t)b * NN * NC;
    const float* Wo = W + ob * (NC * NK); // uniform
    const unsigned short* nl = nbr + (size_t)row * NK;

    float acc = bias[ob];
    for (int k = 0; k < NK; ++k) {
        const int m = nl[k];
        const float* col = xb + (size_t)m * NC;
        float cv[NC];
#pragma unroll
        for (int c = 0; c < NC; ++c) cv[c] = col[c];
#pragma unroll
        for (int c = 0; c < NC; ++c)
            acc = fmaf(Wo[c * NK + k], cv[c], acc);
    }
    out[(size_t)b * NC * NN + (size_t)ob * NN + n] = acc;
}

extern "C" void kernel_launch(void* const* d_in, const int* in_sizes, int n_in,
                              void* d_out, int out_size, void* d_ws, size_t ws_size,
                              hipStream_t stream) {
    const float* x = (const float*)d_in[0];     // [4][16][8192]
    const float* W = (const float*)d_in[1];     // [16][16][9]
    const float* bias = (const float*)d_in[2];  // [16]
    float* out = (float*)d_out;                 // [4][16][8192]

    char* ws = (char*)d_ws;
    float* xt = (float*)ws;
    float* ns32 = (float*)(ws + OFF_NS);
    float* nsk = (float*)(ws + OFF_NSK);
    unsigned* thrsh = (unsigned*)(ws + OFF_THR);
    unsigned short* nbr = (unsigned short*)(ws + OFF_NBR);
    unsigned short* cand = (unsigned short*)(ws + OFF_CAND);

    auto need = [&](int Q) {
        return (size_t)OFF_CAND + (size_t)NB * NN * (size_t)(Q * LIST) * 2;
    };

    prep_kernel<<<(NB * NN) / 256, 256, 0, stream>>>(x, xt, ns32, nsk, thrsh);

    if (ws_size >= need(16)) {
        topk_kernel<16><<<128 * 16, 256, 0, stream>>>(xt, nsk, thrsh, cand);
        rerank_kernel<16 * LIST><<<128, 256, 0, stream>>>(xt, ns32, cand, nbr);
    } else if (ws_size >= need(8)) {
        topk_kernel<8><<<128 * 8, 256, 0, stream>>>(xt, nsk, thrsh, cand);
        rerank_kernel<8 * LIST><<<128, 256, 0, stream>>>(xt, ns32, cand, nbr);
    } else {
        topk_kernel<4><<<128 * 4, 256, 0, stream>>>(xt, nsk, thrsh, cand);
        rerank_kernel<4 * LIST><<<128, 256, 0, stream>>>(xt, ns32, cand, nbr);
    }
    conv_kernel<<<16 * 128, 256, 0, stream>>>(xt, nbr, W, bias, out);
}